// Round 8
// baseline (228198.584 us; speedup 1.0000x reference)
//
#include <hip/hip_runtime.h>

// Problem constants
#define T_STEPS 512
#define BATCH   256
#define DIN     128
#define DH      512
#define DOUT    128
#define RGRP    16         // rowgroups (BATCH/16), one block each

typedef __attribute__((ext_vector_type(8))) short  short8;   // 8 bf16 (4 VGPRs)
typedef __attribute__((ext_vector_type(4))) float  floatx4;  // MFMA acc

union Pack8 { short8 s; unsigned short h[8]; };
union Pack4 { unsigned long long u; unsigned short h[4]; };

__device__ __forceinline__ float bf2f(unsigned short u) {
    union { unsigned int i; float f; } v; v.i = ((unsigned int)u) << 16; return v.f;
}
// round-half-up: max err 0.5 ulp (tie bias negligible vs 4x error margin)
__device__ __forceinline__ unsigned short f2bf(float f) {
    union { float f; unsigned int i; } v; v.f = f;
    return (unsigned short)((v.i + 0x8000u) >> 16);
}
__device__ __forceinline__ float fast_tanh(float v) {
    float ex = __expf(v + v);
    return 1.f - 2.f / (ex + 1.f);
}

// ---------------------------------------------------------------------------
// Pack row-major fp32 [K][N] into bf16 B-fragment order:
//   Wp[ntile][kc][lane][8], lane = quad*16 + (n&15), j = k&7.
// ---------------------------------------------------------------------------
__global__ void pack_b_kernel(const float* __restrict__ W,
                              unsigned short* __restrict__ Wp, int K, int N) {
    int idx = blockIdx.x * blockDim.x + threadIdx.x;
    if (idx >= K * N) return;
    int k = idx / N, n = idx % N;
    int nt = n >> 4, kc = k >> 5, quad = (k >> 3) & 3, j = k & 7;
    int lane = quad * 16 + (n & 15);
    int KC = K >> 5;
    Wp[((size_t)(nt * KC + kc) * 64 + lane) * 8 + j] = f2bf(W[idx]);
}

// xp2 layout: u64 index [(t*16+rg)*32 + nt][lane] -> 4 bf16
// (rows q*4+r, col nt*16+m) — exactly the rnn epilogue's lane ownership.
__device__ __forceinline__ size_t xpidx(int tb_blk, int nt, int lane) {
    return ((size_t)tb_blk * 32 + nt) * 64 + lane;
}

// ---------------------------------------------------------------------------
// xproj: xp[tb][n] = sum_k xs[tb][k] * W1x[k][n], stored bf16 in the
// pre-swizzled xp2 layout above (coalesced b64 per lane).
// ---------------------------------------------------------------------------
__global__ __launch_bounds__(256) void xproj_kernel(
        const float* __restrict__ xs,
        const unsigned short* __restrict__ W1xp,
        unsigned long long* __restrict__ xq) {
    const int tid  = threadIdx.x;
    const int lane = tid & 63;
    const int w    = tid >> 6;
    const int m    = lane & 15;
    const int q    = lane >> 4;
    const long row0 = (long)blockIdx.x * 16;

    short8 a[4];
#pragma unroll
    for (int kc = 0; kc < 4; ++kc) {
        const float* src = xs + (row0 + m) * DIN + kc * 32 + q * 8;
        Pack8 av;
#pragma unroll
        for (int j = 0; j < 8; ++j) av.h[j] = f2bf(src[j]);
        a[kc] = av.s;
    }

#pragma unroll
    for (int i = 0; i < 8; ++i) {
        const int nt = w * 8 + i;
        floatx4 acc = {0.f, 0.f, 0.f, 0.f};
#pragma unroll
        for (int kc = 0; kc < 4; ++kc) {
            short8 b = *(const short8*)(W1xp + ((size_t)(nt * 4 + kc) * 64 + lane) * 8);
            acc = __builtin_amdgcn_mfma_f32_16x16x32_bf16(a[kc], b, acc, 0, 0, 0);
        }
        Pack4 pk;
#pragma unroll
        for (int r = 0; r < 4; ++r) pk.h[r] = f2bf(acc[r]);
        xq[xpidx(blockIdx.x, nt, lane)] = pk.u;
    }
}

// ---------------------------------------------------------------------------
// Recurrence: 16 blocks x 512 threads (8 waves, 2/SIMD). Wave w owns ntiles
// 4w..4w+3 (64 cols). W1h split (R5's proven register shape):
//   kc 0..7            -> registers (bfr: 8 kc x 4 frags = 128 regs/lane)
//   kc 8..8+LKC-1      -> LDS (Wl, written once)
//   kc 8+LKC..15 (NS)  -> streamed from L2, PERSISTENT 2-buffer pipeline:
//       consume counter parity (t*NS+s)&1 picks the buffer; after consuming
//       kc s we reload that buffer with kc (s+2) mod NS — for s=NS-2,NS-1
//       that's NEXT STEP's first two kcs, issued before the epilogue/barrier
//       so they land during the barrier instead of stalling at loop top.
// Hb double-buffered [2][16][516] (pad +4: measured 0 bank conflicts).
// Block-local only: no atomics, 1 barrier/step.
// ---------------------------------------------------------------------------
template <int LKC>
__global__ __launch_bounds__(512, 2) void rnn_kernel(
        const unsigned long long* __restrict__ xq,
        const unsigned short* __restrict__ W1hp,
        const float* __restrict__ b1p,
        const unsigned short* __restrict__ W2p,
        const float* __restrict__ b2p,
        float* __restrict__ out) {
    extern __shared__ unsigned short smem[];
    unsigned short* Hb = smem;                 // [2][16][516]
    unsigned short* Wl = smem + 2 * 16 * 516;  // [LKC][32 nt][64 lane][8]
#define HROW 516
#define HBUF 8256

    const int tid  = threadIdx.x;
    const int lane = tid & 63;
    const int w    = tid >> 6;      // 0..7
    const int m    = lane & 15;
    const int q    = lane >> 4;
    const int rg   = blockIdx.x;
    const float b1 = b1p[0];
    constexpr int RKC  = 8;         // register-resident kc count (R5-proven)
    constexpr int SKC0 = RKC + LKC; // first streamed kc
    constexpr int NS   = 16 - SKC0; // streamed kc count (>=2)

    // ---- register-resident W1h: wave's 4 ntiles x kc 0..7 (128 regs) ----
    short8 bfr[RKC][4];
#pragma unroll
    for (int kc = 0; kc < RKC; ++kc)
#pragma unroll
        for (int i = 0; i < 4; ++i)
            bfr[kc][i] = *(const short8*)(W1hp +
                ((size_t)((4 * w + i) * 16 + kc) * 64 + lane) * 8);

    // ---- LDS-resident W1h (kc RKC..RKC+LKC-1) ----
    if (LKC > 0) {
        for (int c = tid; c < LKC * 2048; c += 512) {
            int j = c >> 11, r = c & 2047;
            int nt = r >> 6, ln = r & 63;
            *(short8*)&Wl[(size_t)c * 8] =
                *(const short8*)(W1hp + ((size_t)(nt * 16 + RKC + j) * 64 + ln) * 8);
        }
    }

    // ---- h^1 = tanh(xp[0] + b1) -> Hb[0] (wave covers its 64 cols) ----
#pragma unroll
    for (int i = 0; i < 4; ++i) {
        Pack4 xv0; xv0.u = xq[xpidx(rg, 4 * w + i, lane)];
#pragma unroll
        for (int r = 0; r < 4; ++r)
            Hb[(q * 4 + r) * HROW + (4 * w + i) * 16 + m] =
                f2bf(fast_tanh(bf2f(xv0.h[r]) + b1));
    }

    // ---- persistent preloads for t=1 ----
    // streamed pipeline invariant at loop top of step t:
    //   sb[(t*NS+0)&1] holds kc SKC0, sb[(t*NS+1)&1] holds kc SKC0+1
    short8 sb[2][4];
#pragma unroll
    for (int u = 0; u < 2; ++u) {
        int buf = (1 * NS + u) & 1;
#pragma unroll
        for (int i = 0; i < 4; ++i)
            sb[buf][i] = *(const short8*)(W1hp +
                ((size_t)((4 * w + i) * 16 + SKC0 + u) * 64 + lane) * 8);
    }
    Pack4 xv[4];
#pragma unroll
    for (int i = 0; i < 4; ++i)
        xv[i].u = xq[xpidx(1 * 16 + rg, 4 * w + i, lane)];

    __syncthreads();

    int p = 0;
#pragma unroll 1
    for (int t = 1; t < T_STEPS; ++t) {
        floatx4 acc[4];
#pragma unroll
        for (int i = 0; i < 4; ++i) acc[i] = (floatx4){0.f, 0.f, 0.f, 0.f};

        // register kcs
#pragma unroll
        for (int kc = 0; kc < RKC; ++kc) {
            short8 a = *(const short8*)&Hb[p * HBUF + m * HROW + kc * 32 + q * 8];
#pragma unroll
            for (int i = 0; i < 4; ++i)
                acc[i] = __builtin_amdgcn_mfma_f32_16x16x32_bf16(a, bfr[kc][i], acc[i], 0, 0, 0);
        }
        // LDS kcs
#pragma unroll
        for (int j = 0; j < LKC; ++j) {
            short8 a = *(const short8*)&Hb[p * HBUF + m * HROW + (RKC + j) * 32 + q * 8];
#pragma unroll
            for (int i = 0; i < 4; ++i) {
                short8 b = *(const short8*)&Wl[((size_t)(j * 32 + 4 * w + i) * 64 + lane) * 8];
                acc[i] = __builtin_amdgcn_mfma_f32_16x16x32_bf16(a, b, acc[i], 0, 0, 0);
            }
        }
        // streamed kcs: consume buffer (parity (t*NS+s)&1), then reload it
        // with kc (s+2) mod NS — wrapping into NEXT step's first two kcs.
#pragma unroll
        for (int s = 0; s < NS; ++s) {
            const int buf = (t * NS + s) & 1;
            short8 a = *(const short8*)&Hb[p * HBUF + m * HROW + (SKC0 + s) * 32 + q * 8];
#pragma unroll
            for (int i = 0; i < 4; ++i)
                acc[i] = __builtin_amdgcn_mfma_f32_16x16x32_bf16(a, sb[buf][i], acc[i], 0, 0, 0);
            const int kc_r = SKC0 + ((s + 2) % NS);
#pragma unroll
            for (int i = 0; i < 4; ++i)
                sb[buf][i] = *(const short8*)(W1hp +
                    ((size_t)((4 * w + i) * 16 + kc_r) * 64 + lane) * 8);
        }

        // epilogue: h^{t+1} -> other buffer (measured conflict-free scatter)
        unsigned short* hd = &Hb[(1 - p) * HBUF];
#pragma unroll
        for (int i = 0; i < 4; ++i)
#pragma unroll
            for (int r = 0; r < 4; ++r) {
                float v = acc[i][r] + bf2f(xv[i].h[r]) + b1;
                hd[(q * 4 + r) * HROW + (4 * w + i) * 16 + m] = f2bf(fast_tanh(v));
            }

        // next-step xv issued pre-barrier (lands during barrier wait)
        const int tn = (t + 1 < T_STEPS) ? t + 1 : t;
#pragma unroll
        for (int i = 0; i < 4; ++i)
            xv[i].u = xq[xpidx(tn * 16 + rg, 4 * w + i, lane)];

        __syncthreads();
        p ^= 1;
    }

    // ---- tail: out[:, 16w..16w+16) = h^512 @ W2 + b2 (packed W2) ----
    const float b2 = b2p[0];
    floatx4 ao = {0.f, 0.f, 0.f, 0.f};
#pragma unroll
    for (int kc = 0; kc < 16; ++kc) {
        short8 a = *(const short8*)&Hb[p * HBUF + m * HROW + kc * 32 + q * 8];
        short8 b = *(const short8*)(W2p + ((size_t)(w * 16 + kc) * 64 + lane) * 8);
        ao = __builtin_amdgcn_mfma_f32_16x16x32_bf16(a, b, ao, 0, 0, 0);
    }
#pragma unroll
    for (int r = 0; r < 4; ++r)
        out[(size_t)(rg * 16 + q * 4 + r) * DOUT + w * 16 + m] = ao[r] + b2;
#undef HROW
#undef HBUF
}

// ---------------------------------------------------------------------------
extern "C" void kernel_launch(void* const* d_in, const int* in_sizes, int n_in,
                              void* d_out, int out_size, void* d_ws, size_t ws_size,
                              hipStream_t stream) {
    const float* xs  = (const float*)d_in[0];
    const float* W1x = (const float*)d_in[1];
    const float* W1h = (const float*)d_in[2];
    const float* b1  = (const float*)d_in[3];
    const float* W2  = (const float*)d_in[4];
    const float* b2  = (const float*)d_in[5];
    float* out = (float*)d_out;

    // ws (bf16 elems): xp2 | W1h packed | W1x packed | W2 packed
    unsigned short* xp2  = (unsigned short*)d_ws;
    unsigned short* w1hp = xp2 + (size_t)T_STEPS * BATCH * DH;     // 67,108,864
    unsigned short* w1xp = w1hp + (size_t)DH * DH;                 // +262,144
    unsigned short* w2p  = w1xp + (size_t)DIN * DH;                // +65,536

    pack_b_kernel<<<(DH * DH + 255) / 256, 256, 0, stream>>>(W1h, w1hp, DH, DH);
    pack_b_kernel<<<(DIN * DH + 255) / 256, 256, 0, stream>>>(W1x, w1xp, DIN, DH);
    pack_b_kernel<<<(DH * DOUT + 255) / 256, 256, 0, stream>>>(W2, w2p, DH, DOUT);
    xproj_kernel<<<(T_STEPS * BATCH) / 16, 256, 0, stream>>>(
        xs, w1xp, (unsigned long long*)xp2);

    // Big: Hb 33,024 B + 3 kc Wl 98,304 B = 131,328 B dynamic LDS (>64 KB
    // opt-in). Fallback: Hb only, stream 8 kc. Deterministic -> graph-safe.
    constexpr size_t SMEM_BIG   = (2 * 16 * 516 + 3 * 2048 * 8) * 2;  // 131328
    constexpr size_t SMEM_SMALL = 2 * 16 * 516 * 2;                   //  33024
    hipError_t e = hipFuncSetAttribute(
        reinterpret_cast<const void*>(&rnn_kernel<3>),
        hipFuncAttributeMaxDynamicSharedMemorySize, (int)SMEM_BIG);
    if (e == hipSuccess) {
        rnn_kernel<3><<<RGRP, 512, SMEM_BIG, stream>>>(
            (const unsigned long long*)xp2, w1hp, b1, w2p, b2, out);
    } else {
        rnn_kernel<0><<<RGRP, 512, SMEM_SMALL, stream>>>(
            (const unsigned long long*)xp2, w1hp, b1, w2p, b2, out);
    }
}

// Round 9
// 2855.662 us; speedup vs baseline: 79.9109x; 79.9109x over previous
//
#include <hip/hip_runtime.h>

// Problem constants
#define T_STEPS 512
#define BATCH   256
#define DIN     128
#define DH      512
#define DOUT    128
#define RGRP    16         // rowgroups (BATCH/16), one block each

typedef __attribute__((ext_vector_type(8))) short  short8;   // 8 bf16 (4 VGPRs)
typedef __attribute__((ext_vector_type(4))) float  floatx4;  // MFMA acc

union Pack8 { short8 s; unsigned short h[8]; };
union Pack4 { unsigned long long u; unsigned short h[4]; };

__device__ __forceinline__ float bf2f(unsigned short u) {
    union { unsigned int i; float f; } v; v.i = ((unsigned int)u) << 16; return v.f;
}
// round-half-up: max err 0.5 ulp (tie bias negligible vs 4x error margin)
__device__ __forceinline__ unsigned short f2bf(float f) {
    union { float f; unsigned int i; } v; v.f = f;
    return (unsigned short)((v.i + 0x8000u) >> 16);
}
__device__ __forceinline__ float fast_tanh(float v) {
    float ex = __expf(v + v);
    return 1.f - 2.f / (ex + 1.f);
}

// ---------------------------------------------------------------------------
// Pack row-major fp32 [K][N] into bf16 B-fragment order:
//   Wp[ntile][kc][lane][8], lane = quad*16 + (n&15), j = k&7.
// ---------------------------------------------------------------------------
__global__ void pack_b_kernel(const float* __restrict__ W,
                              unsigned short* __restrict__ Wp, int K, int N) {
    int idx = blockIdx.x * blockDim.x + threadIdx.x;
    if (idx >= K * N) return;
    int k = idx / N, n = idx % N;
    int nt = n >> 4, kc = k >> 5, quad = (k >> 3) & 3, j = k & 7;
    int lane = quad * 16 + (n & 15);
    int KC = K >> 5;
    Wp[((size_t)(nt * KC + kc) * 64 + lane) * 8 + j] = f2bf(W[idx]);
}

// xp2 layout: u64 index [(t*16+rg)*32 + nt][lane] -> 4 bf16
// (rows q*4+r, col nt*16+m) — exactly the rnn epilogue's lane ownership.
__device__ __forceinline__ size_t xpidx(int tb_blk, int nt, int lane) {
    return ((size_t)tb_blk * 32 + nt) * 64 + lane;
}

// ---------------------------------------------------------------------------
// xproj: xp[tb][n] = sum_k xs[tb][k] * W1x[k][n], stored bf16 in the
// pre-swizzled xp2 layout above (coalesced b64 per lane).
// ---------------------------------------------------------------------------
__global__ __launch_bounds__(256) void xproj_kernel(
        const float* __restrict__ xs,
        const unsigned short* __restrict__ W1xp,
        unsigned long long* __restrict__ xq) {
    const int tid  = threadIdx.x;
    const int lane = tid & 63;
    const int w    = tid >> 6;
    const int m    = lane & 15;
    const int q    = lane >> 4;
    const long row0 = (long)blockIdx.x * 16;

    short8 a[4];
#pragma unroll
    for (int kc = 0; kc < 4; ++kc) {
        const float* src = xs + (row0 + m) * DIN + kc * 32 + q * 8;
        Pack8 av;
#pragma unroll
        for (int j = 0; j < 8; ++j) av.h[j] = f2bf(src[j]);
        a[kc] = av.s;
    }

#pragma unroll
    for (int i = 0; i < 8; ++i) {
        const int nt = w * 8 + i;
        floatx4 acc = {0.f, 0.f, 0.f, 0.f};
#pragma unroll
        for (int kc = 0; kc < 4; ++kc) {
            short8 b = *(const short8*)(W1xp + ((size_t)(nt * 4 + kc) * 64 + lane) * 8);
            acc = __builtin_amdgcn_mfma_f32_16x16x32_bf16(a[kc], b, acc, 0, 0, 0);
        }
        Pack4 pk;
#pragma unroll
        for (int r = 0; r < 4; ++r) pk.h[r] = f2bf(acc[r]);
        xq[xpidx(blockIdx.x, nt, lane)] = pk.u;
    }
}

#define HROW 516
#define HBUF 8256

// ---------------------------------------------------------------------------
// One recurrence step with COMPILE-TIME pipeline parity PAR (= t&1; valid
// because NS=5 is odd so (t*NS+s)&1 == (PAR+s)&1) and COMPILE-TIME Hb index
// P. All sb[] indices constant-fold -> sb stays in registers (R8's runtime
// `t*NS+s` parity demoted sb to scratch: 34 MB/dispatch writes, 100x slower).
// Invariant at entry: sb[(PAR+u)&1] holds kc SKC0+u, u=0,1; xv holds xp[t].
// On exit: invariant holds for t+1 (reloads wrap into next step's kcs and
// are issued BEFORE the barrier, landing while waves wait).
// ---------------------------------------------------------------------------
template <int LKC, int PAR, int P>
__device__ __forceinline__ void rnn_step(
        int t, int rg, int w, int lane, int m, int q, float b1,
        unsigned short* __restrict__ Hb,
        const unsigned short* __restrict__ Wl,
        const unsigned short* __restrict__ W1hp,
        const unsigned long long* __restrict__ xq,
        short8 (&bfr)[8][4], short8 (&sb)[2][4], Pack4 (&xv)[4]) {
    constexpr int RKC  = 8;
    constexpr int SKC0 = RKC + LKC;
    constexpr int NS   = 16 - SKC0;   // 5 (big) or 8 (fallback) — both: see parity note
    static_assert((NS & 1) == 1 || LKC == 0, "parity math assumes NS odd for LKC>0");

    floatx4 acc[4];
#pragma unroll
    for (int i = 0; i < 4; ++i) acc[i] = (floatx4){0.f, 0.f, 0.f, 0.f};

    // register kcs
#pragma unroll
    for (int kc = 0; kc < RKC; ++kc) {
        short8 a = *(const short8*)&Hb[P * HBUF + m * HROW + kc * 32 + q * 8];
#pragma unroll
        for (int i = 0; i < 4; ++i)
            acc[i] = __builtin_amdgcn_mfma_f32_16x16x32_bf16(a, bfr[kc][i], acc[i], 0, 0, 0);
    }
    // LDS kcs
#pragma unroll
    for (int j = 0; j < LKC; ++j) {
        short8 a = *(const short8*)&Hb[P * HBUF + m * HROW + (RKC + j) * 32 + q * 8];
#pragma unroll
        for (int i = 0; i < 4; ++i) {
            short8 b = *(const short8*)&Wl[((size_t)(j * 32 + 4 * w + i) * 64 + lane) * 8];
            acc[i] = __builtin_amdgcn_mfma_f32_16x16x32_bf16(a, b, acc[i], 0, 0, 0);
        }
    }
    // streamed kcs: consume buffer (STATIC parity (PAR+s)&1), then reload it
    // with kc SKC0 + (s+2)%NS — wrapping into next step's first two kcs.
#pragma unroll
    for (int s = 0; s < NS; ++s) {
        const int buf = (PAR + s) & 1;                 // compile-time constant
        short8 a = *(const short8*)&Hb[P * HBUF + m * HROW + (SKC0 + s) * 32 + q * 8];
#pragma unroll
        for (int i = 0; i < 4; ++i)
            acc[i] = __builtin_amdgcn_mfma_f32_16x16x32_bf16(a, sb[buf][i], acc[i], 0, 0, 0);
        const int kc_r = SKC0 + ((s + 2) % NS);        // compile-time constant
#pragma unroll
        for (int i = 0; i < 4; ++i)
            sb[buf][i] = *(const short8*)(W1hp +
                ((size_t)((4 * w + i) * 16 + kc_r) * 64 + lane) * 8);
    }

    // epilogue: h^{t+1} -> other buffer (measured conflict-free scatter)
    unsigned short* hd = &Hb[(1 - P) * HBUF];
#pragma unroll
    for (int i = 0; i < 4; ++i)
#pragma unroll
        for (int r = 0; r < 4; ++r) {
            float v = acc[i][r] + bf2f(xv[i].h[r]) + b1;
            hd[(q * 4 + r) * HROW + (4 * w + i) * 16 + m] = f2bf(fast_tanh(v));
        }

    // next-step xv issued pre-barrier (lands during barrier wait)
    const int tn = (t + 1 < T_STEPS) ? t + 1 : t;
#pragma unroll
    for (int i = 0; i < 4; ++i)
        xv[i].u = xq[xpidx(tn * 16 + rg, 4 * w + i, lane)];

    __syncthreads();
}

// ---------------------------------------------------------------------------
// Recurrence: 16 blocks x 512 threads (8 waves, 2/SIMD). Wave w owns ntiles
// 4w..4w+3 (64 cols). W1h split (R5's proven register shape):
//   kc 0..7       -> registers (bfr: 128 regs/lane)
//   kc 8..10      -> LDS (Wl, written once)     [big variant, LKC=3]
//   kc 11..15     -> streamed from L2, persistent 2-buffer pipeline with
//                    compile-time parity via 2x-unrolled time loop.
// Hb double-buffered [2][16][516] (pad +4: measured 0 bank conflicts).
// Block-local only: no atomics, 1 barrier/step.
// ---------------------------------------------------------------------------
template <int LKC>
__global__ __launch_bounds__(512, 2) void rnn_kernel(
        const unsigned long long* __restrict__ xq,
        const unsigned short* __restrict__ W1hp,
        const float* __restrict__ b1p,
        const unsigned short* __restrict__ W2p,
        const float* __restrict__ b2p,
        float* __restrict__ out) {
    extern __shared__ unsigned short smem[];
    unsigned short* Hb = smem;                 // [2][16][516]
    unsigned short* Wl = smem + 2 * 16 * 516;  // [LKC][32 nt][64 lane][8]

    const int tid  = threadIdx.x;
    const int lane = tid & 63;
    const int w    = tid >> 6;      // 0..7
    const int m    = lane & 15;
    const int q    = lane >> 4;
    const int rg   = blockIdx.x;
    const float b1 = b1p[0];
    constexpr int RKC  = 8;
    constexpr int SKC0 = RKC + LKC;

    // ---- register-resident W1h: wave's 4 ntiles x kc 0..7 (128 regs) ----
    short8 bfr[RKC][4];
#pragma unroll
    for (int kc = 0; kc < RKC; ++kc)
#pragma unroll
        for (int i = 0; i < 4; ++i)
            bfr[kc][i] = *(const short8*)(W1hp +
                ((size_t)((4 * w + i) * 16 + kc) * 64 + lane) * 8);

    // ---- LDS-resident W1h (kc RKC..RKC+LKC-1) ----
    if (LKC > 0) {
        for (int c = tid; c < LKC * 2048; c += 512) {
            int j = c >> 11, r = c & 2047;
            int nt = r >> 6, ln = r & 63;
            *(short8*)&Wl[(size_t)c * 8] =
                *(const short8*)(W1hp + ((size_t)(nt * 16 + RKC + j) * 64 + ln) * 8);
        }
    }

    // ---- h^1 = tanh(xp[0] + b1) -> Hb[0] (wave covers its 64 cols) ----
#pragma unroll
    for (int i = 0; i < 4; ++i) {
        Pack4 xv0; xv0.u = xq[xpidx(rg, 4 * w + i, lane)];
#pragma unroll
        for (int r = 0; r < 4; ++r)
            Hb[(q * 4 + r) * HROW + (4 * w + i) * 16 + m] =
                f2bf(fast_tanh(bf2f(xv0.h[r]) + b1));
    }

    // ---- establish pipeline invariant for t=1 (PAR=1) ----
    short8 sb[2][4];
#pragma unroll
    for (int u = 0; u < 2; ++u) {
        const int buf = (1 + u) & 1;
#pragma unroll
        for (int i = 0; i < 4; ++i)
            sb[buf][i] = *(const short8*)(W1hp +
                ((size_t)((4 * w + i) * 16 + SKC0 + u) * 64 + lane) * 8);
    }
    Pack4 xv[4];
#pragma unroll
    for (int i = 0; i < 4; ++i)
        xv[i].u = xq[xpidx(1 * 16 + rg, 4 * w + i, lane)];

    __syncthreads();

    // ---- time loop, unrolled x2 so PAR and Hb index are compile-time ----
    // steps t=1..511; t odd -> (PAR=1, P=0), t even -> (PAR=0, P=1)
    int t = 1;
#pragma unroll 1
    for (; t + 1 < T_STEPS; t += 2) {
        rnn_step<LKC, 1, 0>(t,     rg, w, lane, m, q, b1, Hb, Wl, W1hp, xq, bfr, sb, xv);
        rnn_step<LKC, 0, 1>(t + 1, rg, w, lane, m, q, b1, Hb, Wl, W1hp, xq, bfr, sb, xv);
    }
    rnn_step<LKC, 1, 0>(t, rg, w, lane, m, q, b1, Hb, Wl, W1hp, xq, bfr, sb, xv);
    // h^512 now in Hb buffer 1

    // ---- tail: out[:, 16w..16w+16) = h^512 @ W2 + b2 (packed W2) ----
    const float b2 = b2p[0];
    floatx4 ao = {0.f, 0.f, 0.f, 0.f};
#pragma unroll
    for (int kc = 0; kc < 16; ++kc) {
        short8 a = *(const short8*)&Hb[HBUF + m * HROW + kc * 32 + q * 8];
        short8 b = *(const short8*)(W2p + ((size_t)(w * 16 + kc) * 64 + lane) * 8);
        ao = __builtin_amdgcn_mfma_f32_16x16x32_bf16(a, b, ao, 0, 0, 0);
    }
#pragma unroll
    for (int r = 0; r < 4; ++r)
        out[(size_t)(rg * 16 + q * 4 + r) * DOUT + w * 16 + m] = ao[r] + b2;
}

// ---------------------------------------------------------------------------
extern "C" void kernel_launch(void* const* d_in, const int* in_sizes, int n_in,
                              void* d_out, int out_size, void* d_ws, size_t ws_size,
                              hipStream_t stream) {
    const float* xs  = (const float*)d_in[0];
    const float* W1x = (const float*)d_in[1];
    const float* W1h = (const float*)d_in[2];
    const float* b1  = (const float*)d_in[3];
    const float* W2  = (const float*)d_in[4];
    const float* b2  = (const float*)d_in[5];
    float* out = (float*)d_out;

    // ws (bf16 elems): xp2 | W1h packed | W1x packed | W2 packed
    unsigned short* xp2  = (unsigned short*)d_ws;
    unsigned short* w1hp = xp2 + (size_t)T_STEPS * BATCH * DH;     // 67,108,864
    unsigned short* w1xp = w1hp + (size_t)DH * DH;                 // +262,144
    unsigned short* w2p  = w1xp + (size_t)DIN * DH;                // +65,536

    pack_b_kernel<<<(DH * DH + 255) / 256, 256, 0, stream>>>(W1h, w1hp, DH, DH);
    pack_b_kernel<<<(DIN * DH + 255) / 256, 256, 0, stream>>>(W1x, w1xp, DIN, DH);
    pack_b_kernel<<<(DH * DOUT + 255) / 256, 256, 0, stream>>>(W2, w2p, DH, DOUT);
    xproj_kernel<<<(T_STEPS * BATCH) / 16, 256, 0, stream>>>(
        xs, w1xp, (unsigned long long*)xp2);

    // Big: Hb 33,024 B + 3 kc Wl 98,304 B = 131,328 B dynamic LDS (>64 KB
    // opt-in). Fallback: Hb only, stream 8 kc. Deterministic -> graph-safe.
    constexpr size_t SMEM_BIG   = (2 * 16 * 516 + 3 * 2048 * 8) * 2;  // 131328
    constexpr size_t SMEM_SMALL = 2 * 16 * 516 * 2;                   //  33024
    hipError_t e = hipFuncSetAttribute(
        reinterpret_cast<const void*>(&rnn_kernel<3>),
        hipFuncAttributeMaxDynamicSharedMemorySize, (int)SMEM_BIG);
    if (e == hipSuccess) {
        rnn_kernel<3><<<RGRP, 512, SMEM_BIG, stream>>>(
            (const unsigned long long*)xp2, w1hp, b1, w2p, b2, out);
    } else {
        rnn_kernel<0><<<RGRP, 512, SMEM_SMALL, stream>>>(
            (const unsigned long long*)xp2, w1hp, b1, w2p, b2, out);
    }
}

// Round 10
// 2662.134 us; speedup vs baseline: 85.7202x; 1.0727x over previous
//
#include <hip/hip_runtime.h>

// Problem constants
#define T_STEPS 512
#define BATCH   256
#define DIN     128
#define DH      512
#define DOUT    128
#define RGRP    16         // rowgroups (BATCH/16), one block each

typedef __attribute__((ext_vector_type(8))) short  short8;   // 8 bf16 (4 VGPRs)
typedef __attribute__((ext_vector_type(4))) float  floatx4;  // MFMA acc

union Pack8 { short8 s; unsigned short h[8]; };
union Pack4 { unsigned long long u; unsigned short h[4]; };

__device__ __forceinline__ float bf2f(unsigned short u) {
    union { unsigned int i; float f; } v; v.i = ((unsigned int)u) << 16; return v.f;
}
// round-half-up: max err 0.5 ulp (tie bias negligible vs 4x error margin)
__device__ __forceinline__ unsigned short f2bf(float f) {
    union { float f; unsigned int i; } v; v.f = f;
    return (unsigned short)((v.i + 0x8000u) >> 16);
}
__device__ __forceinline__ float fast_tanh(float v) {
    float ex = __expf(v + v);
    return 1.f - 2.f / (ex + 1.f);
}

// ---------------------------------------------------------------------------
// Pack row-major fp32 [K][N] into bf16 B-fragment order:
//   Wp[ntile][kc][lane][8], lane = quad*16 + (n&15), j = k&7.
// ---------------------------------------------------------------------------
__global__ void pack_b_kernel(const float* __restrict__ W,
                              unsigned short* __restrict__ Wp, int K, int N) {
    int idx = blockIdx.x * blockDim.x + threadIdx.x;
    if (idx >= K * N) return;
    int k = idx / N, n = idx % N;
    int nt = n >> 4, kc = k >> 5, quad = (k >> 3) & 3, j = k & 7;
    int lane = quad * 16 + (n & 15);
    int KC = K >> 5;
    Wp[((size_t)(nt * KC + kc) * 64 + lane) * 8 + j] = f2bf(W[idx]);
}

// xp2 layout: u64 index [(t*16+rg)*32 + nt][lane] -> 4 bf16
// (rows q*4+r, col nt*16+m) — exactly the rnn epilogue's lane ownership.
__device__ __forceinline__ size_t xpidx(int tb_blk, int nt, int lane) {
    return ((size_t)tb_blk * 32 + nt) * 64 + lane;
}

// ---------------------------------------------------------------------------
// xproj: xp[tb][n] = sum_k xs[tb][k] * W1x[k][n], stored bf16 in the
// pre-swizzled xp2 layout above (coalesced b64 per lane).
// ---------------------------------------------------------------------------
__global__ __launch_bounds__(256) void xproj_kernel(
        const float* __restrict__ xs,
        const unsigned short* __restrict__ W1xp,
        unsigned long long* __restrict__ xq) {
    const int tid  = threadIdx.x;
    const int lane = tid & 63;
    const int w    = tid >> 6;
    const int m    = lane & 15;
    const int q    = lane >> 4;
    const long row0 = (long)blockIdx.x * 16;

    short8 a[4];
#pragma unroll
    for (int kc = 0; kc < 4; ++kc) {
        const float* src = xs + (row0 + m) * DIN + kc * 32 + q * 8;
        Pack8 av;
#pragma unroll
        for (int j = 0; j < 8; ++j) av.h[j] = f2bf(src[j]);
        a[kc] = av.s;
    }

#pragma unroll
    for (int i = 0; i < 8; ++i) {
        const int nt = w * 8 + i;
        floatx4 acc = {0.f, 0.f, 0.f, 0.f};
#pragma unroll
        for (int kc = 0; kc < 4; ++kc) {
            short8 b = *(const short8*)(W1xp + ((size_t)(nt * 4 + kc) * 64 + lane) * 8);
            acc = __builtin_amdgcn_mfma_f32_16x16x32_bf16(a[kc], b, acc, 0, 0, 0);
        }
        Pack4 pk;
#pragma unroll
        for (int r = 0; r < 4; ++r) pk.h[r] = f2bf(acc[r]);
        xq[xpidx(blockIdx.x, nt, lane)] = pk.u;
    }
}

// ---------------------------------------------------------------------------
// Recurrence — EXACT R5 structure (the 1513 us / 2.96 us-step schedule):
// 16 blocks x 512 threads (8 waves, 2/SIMD). Wave w owns ntiles 4w..4w+3.
// W1h split: kc 0..7 registers (bfr, 128 regs) | kc 8..10 LDS (Wl) |
// kc 11..15 streamed in 2-kc groups, sb[2][2][4]: groups g0,g1 preloaded at
// LOOP TOP (covered by the 11 reg/LDS-kc MFMAs), consume g then reload g+2.
// Micro-opts vs R5 (independently proven safe in R6/R7/R9):
//   - Hb pad 516 (R5's 520 cost ~4.2M bank-conflict cycles; 516 measured 0)
//   - xq pre-swizzled xp: 4 coalesced b64 loads replace 16 scalar u16 loads
//   - 2-op f2bf, packed-W2 MFMA tail
// Block-local only: no atomics, 1 barrier/step, runtime Hb ping-pong index.
// ---------------------------------------------------------------------------
#define HROW 516
#define HBUF 8256

template <int LKC>
__global__ __launch_bounds__(512, 2) void rnn_kernel(
        const unsigned long long* __restrict__ xq,
        const unsigned short* __restrict__ W1hp,
        const float* __restrict__ b1p,
        const unsigned short* __restrict__ W2p,
        const float* __restrict__ b2p,
        float* __restrict__ out) {
    extern __shared__ unsigned short smem[];
    unsigned short* Hb = smem;                 // [2][16][516]
    unsigned short* Wl = smem + 2 * 16 * 516;  // [LKC][32 nt][64 lane][8]

    const int tid  = threadIdx.x;
    const int lane = tid & 63;
    const int w    = tid >> 6;      // 0..7
    const int m    = lane & 15;
    const int q    = lane >> 4;
    const int rg   = blockIdx.x;
    const float b1 = b1p[0];
    constexpr int RKC = 8;                 // register-resident kc count
    constexpr int KB  = RKC + LKC;         // first streamed kc
    constexpr int NG  = (8 - LKC + 1) / 2; // 2-kc streamed groups

    // ---- register-resident W1h: wave's 4 ntiles x kc 0..7 (128 regs) ----
    short8 bfr[RKC][4];
#pragma unroll
    for (int kc = 0; kc < RKC; ++kc)
#pragma unroll
        for (int i = 0; i < 4; ++i)
            bfr[kc][i] = *(const short8*)(W1hp +
                ((size_t)((4 * w + i) * 16 + kc) * 64 + lane) * 8);

    // ---- LDS-resident W1h (kc RKC..RKC+LKC-1) ----
    if (LKC > 0) {
        for (int c = tid; c < LKC * 2048; c += 512) {
            int j = c >> 11, r = c & 2047;
            int nt = r >> 6, ln = r & 63;
            *(short8*)&Wl[(size_t)c * 8] =
                *(const short8*)(W1hp + ((size_t)(nt * 16 + RKC + j) * 64 + ln) * 8);
        }
    }

    // ---- h^1 = tanh(xp[0] + b1) -> Hb[0] (wave covers its 64 cols) ----
#pragma unroll
    for (int i = 0; i < 4; ++i) {
        Pack4 xv0; xv0.u = xq[xpidx(rg, 4 * w + i, lane)];
#pragma unroll
        for (int r = 0; r < 4; ++r)
            Hb[(q * 4 + r) * HROW + (4 * w + i) * 16 + m] =
                f2bf(fast_tanh(bf2f(xv0.h[r]) + b1));
    }
    __syncthreads();

    int p = 0;
#pragma unroll 1
    for (int t = 1; t < T_STEPS; ++t) {
        // xp[t]: 4 coalesced b64 loads (HBM latency hidden under the body)
        Pack4 xv[4];
#pragma unroll
        for (int i = 0; i < 4; ++i)
            xv[i].u = xq[xpidx(t * 16 + rg, 4 * w + i, lane)];

        // streamed pipeline: preload groups 0 and 1 at loop top (L2-resident;
        // latency covered by the 11 register/LDS-kc MFMAs below)
        short8 sb[2][2][4];
#pragma unroll
        for (int g = 0; g < 2 && g < NG; ++g)
#pragma unroll
            for (int c = 0; c < 2; ++c) {
                int kc = KB + 2 * g + c;
                if (kc < 16)
#pragma unroll
                    for (int i = 0; i < 4; ++i)
                        sb[g][c][i] = *(const short8*)(W1hp +
                            ((size_t)((4 * w + i) * 16 + kc) * 64 + lane) * 8);
            }

        floatx4 acc[4];
#pragma unroll
        for (int i = 0; i < 4; ++i) acc[i] = (floatx4){0.f, 0.f, 0.f, 0.f};

        // register kcs
#pragma unroll
        for (int kc = 0; kc < RKC; ++kc) {
            short8 a = *(const short8*)&Hb[p * HBUF + m * HROW + kc * 32 + q * 8];
#pragma unroll
            for (int i = 0; i < 4; ++i)
                acc[i] = __builtin_amdgcn_mfma_f32_16x16x32_bf16(a, bfr[kc][i], acc[i], 0, 0, 0);
        }
        // LDS kcs
#pragma unroll
        for (int j = 0; j < LKC; ++j) {
            short8 a = *(const short8*)&Hb[p * HBUF + m * HROW + (RKC + j) * 32 + q * 8];
#pragma unroll
            for (int i = 0; i < 4; ++i) {
                short8 b = *(const short8*)&Wl[((size_t)(j * 32 + 4 * w + i) * 64 + lane) * 8];
                acc[i] = __builtin_amdgcn_mfma_f32_16x16x32_bf16(a, b, acc[i], 0, 0, 0);
            }
        }
        // streamed kcs: consume group g FIRST, then reload its buffer with
        // group g+2 (they alias: (g+2)&1 == g&1) — R5-proven order.
#pragma unroll
        for (int g = 0; g < NG; ++g) {
#pragma unroll
            for (int c = 0; c < 2; ++c) {
                int kc = KB + 2 * g + c;
                if (kc < 16) {
                    short8 a = *(const short8*)&Hb[p * HBUF + m * HROW + kc * 32 + q * 8];
#pragma unroll
                    for (int i = 0; i < 4; ++i)
                        acc[i] = __builtin_amdgcn_mfma_f32_16x16x32_bf16(a, sb[g & 1][c][i], acc[i], 0, 0, 0);
                }
            }
            if (g + 2 < NG) {
#pragma unroll
                for (int c = 0; c < 2; ++c) {
                    int kc = KB + 2 * (g + 2) + c;
                    if (kc < 16)
#pragma unroll
                        for (int i = 0; i < 4; ++i)
                            sb[g & 1][c][i] = *(const short8*)(W1hp +
                                ((size_t)((4 * w + i) * 16 + kc) * 64 + lane) * 8);
                }
            }
        }

        // epilogue: h^{t+1} -> other buffer (pad 516: measured conflict-free)
        unsigned short* hd = &Hb[(1 - p) * HBUF];
#pragma unroll
        for (int i = 0; i < 4; ++i)
#pragma unroll
            for (int r = 0; r < 4; ++r) {
                float v = acc[i][r] + bf2f(xv[i].h[r]) + b1;
                hd[(q * 4 + r) * HROW + (4 * w + i) * 16 + m] = f2bf(fast_tanh(v));
            }
        __syncthreads();
        p ^= 1;
    }

    // ---- tail: out[:, 16w..16w+16) = h^512 @ W2 + b2 (packed W2) ----
    const float b2 = b2p[0];
    floatx4 ao = {0.f, 0.f, 0.f, 0.f};
#pragma unroll
    for (int kc = 0; kc < 16; ++kc) {
        short8 a = *(const short8*)&Hb[p * HBUF + m * HROW + kc * 32 + q * 8];
        short8 b = *(const short8*)(W2p + ((size_t)(w * 16 + kc) * 64 + lane) * 8);
        ao = __builtin_amdgcn_mfma_f32_16x16x32_bf16(a, b, ao, 0, 0, 0);
    }
#pragma unroll
    for (int r = 0; r < 4; ++r)
        out[(size_t)(rg * 16 + q * 4 + r) * DOUT + w * 16 + m] = ao[r] + b2;
}

// ---------------------------------------------------------------------------
extern "C" void kernel_launch(void* const* d_in, const int* in_sizes, int n_in,
                              void* d_out, int out_size, void* d_ws, size_t ws_size,
                              hipStream_t stream) {
    const float* xs  = (const float*)d_in[0];
    const float* W1x = (const float*)d_in[1];
    const float* W1h = (const float*)d_in[2];
    const float* b1  = (const float*)d_in[3];
    const float* W2  = (const float*)d_in[4];
    const float* b2  = (const float*)d_in[5];
    float* out = (float*)d_out;

    // ws (bf16 elems): xp2 | W1h packed | W1x packed | W2 packed
    unsigned short* xp2  = (unsigned short*)d_ws;
    unsigned short* w1hp = xp2 + (size_t)T_STEPS * BATCH * DH;     // 67,108,864
    unsigned short* w1xp = w1hp + (size_t)DH * DH;                 // +262,144
    unsigned short* w2p  = w1xp + (size_t)DIN * DH;                // +65,536

    pack_b_kernel<<<(DH * DH + 255) / 256, 256, 0, stream>>>(W1h, w1hp, DH, DH);
    pack_b_kernel<<<(DIN * DH + 255) / 256, 256, 0, stream>>>(W1x, w1xp, DIN, DH);
    pack_b_kernel<<<(DH * DOUT + 255) / 256, 256, 0, stream>>>(W2, w2p, DH, DOUT);
    xproj_kernel<<<(T_STEPS * BATCH) / 16, 256, 0, stream>>>(
        xs, w1xp, (unsigned long long*)xp2);

    // Big: Hb 33,024 B + 3 kc Wl 98,304 B = 131,328 B dynamic LDS (>64 KB
    // opt-in). Fallback: Hb only, stream 8 kc. Deterministic -> graph-safe.
    constexpr size_t SMEM_BIG   = (2 * 16 * 516 + 3 * 2048 * 8) * 2;  // 131328
    constexpr size_t SMEM_SMALL = 2 * 16 * 516 * 2;                   //  33024
    hipError_t e = hipFuncSetAttribute(
        reinterpret_cast<const void*>(&rnn_kernel<3>),
        hipFuncAttributeMaxDynamicSharedMemorySize, (int)SMEM_BIG);
    if (e == hipSuccess) {
        rnn_kernel<3><<<RGRP, 512, SMEM_BIG, stream>>>(
            (const unsigned long long*)xp2, w1hp, b1, w2p, b2, out);
    } else {
        rnn_kernel<0><<<RGRP, 512, SMEM_SMALL, stream>>>(
            (const unsigned long long*)xp2, w1hp, b1, w2p, b2, out);
    }
}